// Round 1
// baseline (2035.991 us; speedup 1.0000x reference)
//
#include <hip/hip_runtime.h>
#include <hip/hip_bf16.h>

#define N 4096
#define M 128
#define KK 32
#define G 16
#define NCH 8
#define CHUNK (N / NCH)   // 512
#define W_EPS 1e-6f

// ---------------------------------------------------------------------------
// Kernel 1: per-child i: oc = mean_g omega_child[i,g,:,:]; mu = mean_g mu_s;
//           solve oc * v = mu (Gauss-Jordan, column-per-lane in registers).
// One block per child. Phase A uses all 256 threads (coalesced float4 stream);
// phase B uses wave 0 (lanes 0-31 own columns, lanes 32-63 redundant copies).
// ---------------------------------------------------------------------------
__global__ __launch_bounds__(256) void k1_reduce_solve(
    const float* __restrict__ omega_child,
    const float* __restrict__ mu_s,
    float* __restrict__ v_out)
{
    __shared__ float oc[KK * KK];
    __shared__ float mu[KK];
    const int i = blockIdx.x;
    const int t = threadIdx.x;
    const float inv_g = 1.0f / G;

    // Phase A: reduce omega_child over G. 16 coalesced float4 loads/thread.
    {
        const float4* src4 = (const float4*)omega_child + (size_t)i * (G * KK * KK / 4);
        float ax = 0.f, ay = 0.f, az = 0.f, aw = 0.f;
        #pragma unroll
        for (int g = 0; g < G; ++g) {
            float4 x = src4[g * (KK * KK / 4) + t];
            ax += x.x; ay += x.y; az += x.z; aw += x.w;
        }
        float4 o; o.x = ax * inv_g; o.y = ay * inv_g; o.z = az * inv_g; o.w = aw * inv_g;
        ((float4*)oc)[t] = o;
    }
    // reduce mu_s over G (lanes 0-31, 128B coalesced per g)
    if (t < KK) {
        const float* m = mu_s + (size_t)i * G * KK + t;
        float acc = 0.f;
        #pragma unroll
        for (int g = 0; g < G; ++g) acc += m[g * KK];
        mu[t] = acc * inv_g;
    }
    __syncthreads();

    // Phase B: Gauss-Jordan solve, column c in lane c's registers.
    if (t < 64) {
        const int c    = t & 31;
        const int base = t & 32;   // upper half-wave shuffles among itself
        float A[KK], rhs[KK];
        #pragma unroll
        for (int r = 0; r < KK; ++r) { A[r] = oc[r * KK + c]; rhs[r] = mu[r]; }

        // forward elimination (SPD, diagonally dominant-ish: no pivoting)
        #pragma unroll
        for (int p = 0; p < KK; ++p) {
            float App = __shfl(A[p], p + base);
            float invApp = 1.0f / App;
            #pragma unroll
            for (int r = p + 1; r < KK; ++r) {
                float f = __shfl(A[r], p + base) * invApp;  // A[r][p]/A[p][p]
                A[r]   -= f * A[p];
                rhs[r] -= f * rhs[p];
            }
        }
        // back substitution (rhs replicated across lanes)
        #pragma unroll
        for (int p = KK - 1; p >= 0; --p) {
            float App = __shfl(A[p], p + base);
            rhs[p] *= (1.0f / App);
            #pragma unroll
            for (int r = 0; r < p; ++r) {
                float Arp = __shfl(A[r], p + base);  // U[r][p]
                rhs[r] -= Arp * rhs[p];
            }
        }
        // lane c writes v[i][c]: static-index select (avoids scratch spill)
        if (t < KK) {
            float mine = rhs[0];
            #pragma unroll
            for (int r = 1; r < KK; ++r) mine = (c == r) ? rhs[r] : mine;
            v_out[(size_t)i * KK + c] = mine;
        }
    }
}

// ---------------------------------------------------------------------------
// Kernel 2: per (cluster a, i-chunk): w[a,i] = mean_g W[i,a,g] (masked),
//           accumulate R += w * v v^T, s += w * v, Z += w, count += mask.
// Deterministic partials (no atomics): grid (M, NCH).
// ---------------------------------------------------------------------------
__global__ __launch_bounds__(256) void k2_accumulate(
    const float* __restrict__ W,
    const float* __restrict__ v,
    float* __restrict__ R_part,
    float* __restrict__ s_part,
    float* __restrict__ Z_part,
    float* __restrict__ cnt_part)
{
    __shared__ float w_lds[32];
    __shared__ float v_lds[32 * KK];
    __shared__ float red_z[4], red_c[4];
    const int a  = blockIdx.x;
    const int ch = blockIdx.y;
    const int t  = threadIdx.x;
    const int k0 = t >> 3;       // 0..31: row of R this thread owns
    const int l8 = t & 7;        // float4 column group 0..7

    float accx = 0.f, accy = 0.f, accz = 0.f, accw = 0.f;
    float s_acc = 0.f, z_acc = 0.f, c_acc = 0.f;

    for (int tile = 0; tile < CHUNK / 32; ++tile) {
        const int ib = ch * CHUNK + tile * 32;

        // stage w for 32 children: 16-lane groups reduce over g
        #pragma unroll
        for (int pass = 0; pass < 2; ++pass) {
            int i_off = pass * 16 + (t >> 4);
            int g = t & 15;
            float val = W[(size_t)(ib + i_off) * (M * G) + a * G + g];
            val += __shfl_xor(val, 1);
            val += __shfl_xor(val, 2);
            val += __shfl_xor(val, 4);
            val += __shfl_xor(val, 8);
            if (g == 0) {
                float wsc = val * (1.0f / G);
                bool  mk  = wsc >= W_EPS;
                float wm  = mk ? wsc : 0.0f;
                w_lds[i_off] = wm;
                z_acc += wm;
                c_acc += mk ? 1.0f : 0.0f;
            }
        }
        // stage v for 32 children (coalesced float4)
        ((float4*)v_lds)[t] = ((const float4*)v)[ib * 8 + t];
        __syncthreads();

        #pragma unroll
        for (int ii = 0; ii < 32; ++ii) {
            float w  = w_lds[ii];
            float vk = v_lds[ii * KK + k0];
            float4 vl = ((const float4*)v_lds)[ii * 8 + l8];
            float wv = w * vk;
            accx += wv * vl.x; accy += wv * vl.y;
            accz += wv * vl.z; accw += wv * vl.w;
            if (l8 == 0) s_acc += wv;   // thread (k0, l8==0) owns s[k0]
        }
        __syncthreads();
    }

    float4 o; o.x = accx; o.y = accy; o.z = accz; o.w = accw;
    ((float4*)R_part)[((size_t)a * NCH + ch) * 256 + t] = o;
    if (l8 == 0) s_part[((size_t)a * NCH + ch) * KK + k0] = s_acc;

    // block reduce Z / count
    #pragma unroll
    for (int off = 32; off >= 1; off >>= 1) {
        z_acc += __shfl_down(z_acc, off);
        c_acc += __shfl_down(c_acc, off);
    }
    if ((t & 63) == 0) { red_z[t >> 6] = z_acc; red_c[t >> 6] = c_acc; }
    __syncthreads();
    if (t == 0) {
        Z_part[(size_t)a * NCH + ch]   = red_z[0] + red_z[1] + red_z[2] + red_z[3];
        cnt_part[(size_t)a * NCH + ch] = red_c[0] + red_c[1] + red_c[2] + red_c[3];
    }
}

// ---------------------------------------------------------------------------
// Kernel 3: per cluster a: op = mean_g omega_parent; reduce partials;
//           t = op @ s; qr = <op^T op, R>; psi = qr/Zs - ||t||^2/Zs^2 (Z>0),
//           gated on count >= 2. Final scalars in double.
// ---------------------------------------------------------------------------
__global__ __launch_bounds__(256) void k3_finalize(
    const float* __restrict__ omega_parent,
    const float* __restrict__ R_part,
    const float* __restrict__ s_part,
    const float* __restrict__ Z_part,
    const float* __restrict__ cnt_part,
    float* __restrict__ out)
{
    __shared__ float op_lds[KK * KK];
    __shared__ float R_lds[KK * KK];
    __shared__ float s_lds[KK];
    __shared__ float t_lds[KK];
    __shared__ float zc[2];
    __shared__ double dred[4];
    const int a = blockIdx.x;
    const int t = threadIdx.x;

    {   // reduce omega_parent over G
        const float4* src4 = (const float4*)omega_parent + (size_t)a * (G * KK * KK / 4);
        float ax = 0.f, ay = 0.f, az = 0.f, aw = 0.f;
        #pragma unroll
        for (int g = 0; g < G; ++g) {
            float4 x = src4[g * (KK * KK / 4) + t];
            ax += x.x; ay += x.y; az += x.z; aw += x.w;
        }
        const float s = 1.0f / G;
        float4 o; o.x = ax * s; o.y = ay * s; o.z = az * s; o.w = aw * s;
        ((float4*)op_lds)[t] = o;
    }
    {   // reduce R partials
        float ax = 0.f, ay = 0.f, az = 0.f, aw = 0.f;
        #pragma unroll
        for (int c = 0; c < NCH; ++c) {
            float4 x = ((const float4*)R_part)[((size_t)a * NCH + c) * 256 + t];
            ax += x.x; ay += x.y; az += x.z; aw += x.w;
        }
        float4 o; o.x = ax; o.y = ay; o.z = az; o.w = aw;
        ((float4*)R_lds)[t] = o;
    }
    if (t < KK) {
        float sv = 0.f;
        #pragma unroll
        for (int c = 0; c < NCH; ++c) sv += s_part[((size_t)a * NCH + c) * KK + t];
        s_lds[t] = sv;
    }
    if (t == 0) {
        float Z = 0.f, C = 0.f;
        #pragma unroll
        for (int c = 0; c < NCH; ++c) { Z += Z_part[a * NCH + c]; C += cnt_part[a * NCH + c]; }
        zc[0] = Z; zc[1] = C;
    }
    __syncthreads();

    if (t < KK) {   // t_vec = op @ s
        float tv = 0.f;
        #pragma unroll
        for (int l = 0; l < KK; ++l) tv += op_lds[t * KK + l] * s_lds[l];
        t_lds[t] = tv;
    }

    // <Q,R> = sum_{j,l} (op@R)[j,l] * op[j,l]; thread owns (j, 4 l's)
    const int j  = t >> 3;
    const int l8 = t & 7;
    float dx = 0.f, dy = 0.f, dz = 0.f, dw = 0.f;
    #pragma unroll
    for (int k = 0; k < KK; ++k) {
        float o = op_lds[j * KK + k];
        float4 rr = ((const float4*)R_lds)[k * 8 + l8];
        dx += o * rr.x; dy += o * rr.y; dz += o * rr.z; dw += o * rr.w;
    }
    const int l0 = l8 * 4;
    double part = (double)dx * op_lds[j * KK + l0]
                + (double)dy * op_lds[j * KK + l0 + 1]
                + (double)dz * op_lds[j * KK + l0 + 2]
                + (double)dw * op_lds[j * KK + l0 + 3];
    #pragma unroll
    for (int off = 32; off >= 1; off >>= 1) part += __shfl_down(part, off);
    if ((t & 63) == 0) dred[t >> 6] = part;
    __syncthreads();

    if (t == 0) {
        double qr = dred[0] + dred[1] + dred[2] + dred[3];
        double tt = 0.0;
        #pragma unroll
        for (int k = 0; k < KK; ++k) tt += (double)t_lds[k] * (double)t_lds[k];
        double Z  = (double)zc[0];
        double C  = (double)zc[1];
        double Zs = (Z > 0.0) ? Z : 1.0;
        // psi*Zs = <Q,R> - 2*||t||^2/Zs + Z*||t||^2/Zs^2   (exact for both Z>0 and Z==0)
        double psi = qr / Zs - 2.0 * tt / (Zs * Zs) + Z * tt / (Zs * Zs * Zs);
        out[a] = (C >= 2.0) ? (float)psi : 0.0f;
    }
}

// ---------------------------------------------------------------------------
extern "C" void kernel_launch(void* const* d_in, const int* in_sizes, int n_in,
                              void* d_out, int out_size, void* d_ws, size_t ws_size,
                              hipStream_t stream) {
    const float* W_in  = (const float*)d_in[0];   // (N, M, G)
    const float* mu_in = (const float*)d_in[1];   // (N, G, K)
    const float* oc_in = (const float*)d_in[2];   // (N, G, K, K)
    const float* op_in = (const float*)d_in[3];   // (M, G, K, K)
    float* out = (float*)d_out;                   // (M,)

    // workspace layout (floats), total ~4.9 MB; every element written before read
    float* v        = (float*)d_ws;                       // N*K
    float* R_part   = v + (size_t)N * KK;                 // M*NCH*K*K
    float* s_part   = R_part + (size_t)M * NCH * KK * KK; // M*NCH*K
    float* Z_part   = s_part + (size_t)M * NCH * KK;      // M*NCH
    float* cnt_part = Z_part + (size_t)M * NCH;           // M*NCH

    k1_reduce_solve<<<N, 256, 0, stream>>>(oc_in, mu_in, v);
    k2_accumulate<<<dim3(M, NCH), 256, 0, stream>>>(W_in, v, R_part, s_part, Z_part, cnt_part);
    k3_finalize<<<M, 256, 0, stream>>>(op_in, R_part, s_part, Z_part, cnt_part, out);
}

// Round 2
// 479.941 us; speedup vs baseline: 4.2422x; 4.2422x over previous
//
#include <hip/hip_runtime.h>
#include <hip/hip_bf16.h>

#define N 4096
#define M 128
#define KK 32
#define G 16
#define NCH 8
#define CHUNK (N / NCH)   // 512
#define TILE 256
#define W_EPS 1e-6f
#define NIT 40

// ---------------------------------------------------------------------------
// Kernel 1: one WAVE per child i.
//   Lane l holds floats [16l, 16l+16) of oc_avg = row (l>>1), cols [16*(l&1),+16).
//   -> every load instruction is a contiguous 1KB wave transaction.
//   Solve oc*v = mu via Richardson iteration (spectrum ~[1.56,2.56], alpha=0.476,
//   rho<=0.27; 40 iters -> far below fp32 ulp). ~30 VGPRs, no LDS, no spill.
// ---------------------------------------------------------------------------
__global__ __launch_bounds__(256) void k1_reduce_solve(
    const float* __restrict__ omega_child,
    const float* __restrict__ mu_s,
    float* __restrict__ v_out)
{
    const int wave = threadIdx.x >> 6;
    const int lane = threadIdx.x & 63;
    const int i = blockIdx.x * 4 + wave;
    const float inv_g = 1.0f / G;

    // reduce omega_child[i] over G into 16 per-lane registers
    float r0=0.f,r1=0.f,r2=0.f,r3=0.f,r4=0.f,r5=0.f,r6=0.f,r7=0.f;
    float r8=0.f,r9=0.f,r10=0.f,r11=0.f,r12=0.f,r13=0.f,r14=0.f,r15=0.f;
    {
        const float4* src = (const float4*)(omega_child + (size_t)i * (G * KK * KK)) + lane * 4;
        #pragma unroll
        for (int g = 0; g < G; ++g) {
            float4 x0 = src[0], x1 = src[1], x2 = src[2], x3 = src[3];
            src += KK * KK / 4;
            r0  += x0.x; r1  += x0.y; r2  += x0.z; r3  += x0.w;
            r4  += x1.x; r5  += x1.y; r6  += x1.z; r7  += x1.w;
            r8  += x2.x; r9  += x2.y; r10 += x2.z; r11 += x2.w;
            r12 += x3.x; r13 += x3.y; r14 += x3.z; r15 += x3.w;
        }
        r0*=inv_g; r1*=inv_g; r2*=inv_g; r3*=inv_g; r4*=inv_g; r5*=inv_g;
        r6*=inv_g; r7*=inv_g; r8*=inv_g; r9*=inv_g; r10*=inv_g; r11*=inv_g;
        r12*=inv_g; r13*=inv_g; r14*=inv_g; r15*=inv_g;
    }

    // reduce mu over G: lane c (&31) accumulates mu[c]; then broadcast row value
    float muc = 0.f;
    {
        const float* mp = mu_s + (size_t)i * (G * KK) + (lane & 31);
        #pragma unroll
        for (int g = 0; g < G; ++g) muc += mp[g * KK];
        muc *= inv_g;
    }
    const float mu_r = __shfl(muc, lane >> 1);   // mu for my row r = lane>>1

    // Richardson: v <- v + alpha*(mu - oc*v). v_r lives in lanes 2r, 2r+1.
    const float alpha = 0.476f;
    const int   h32   = (lane & 1) << 5;         // column-half offset in source lanes
    float v = alpha * mu_r;
    #pragma unroll 1
    for (int it = 0; it < NIT; ++it) {
        float p = 0.f;
        // v_c (c = 16h + j) is held by lane 2c = 32h + 2j
        p += r0  * __shfl(v, h32 +  0); p += r1  * __shfl(v, h32 +  2);
        p += r2  * __shfl(v, h32 +  4); p += r3  * __shfl(v, h32 +  6);
        p += r4  * __shfl(v, h32 +  8); p += r5  * __shfl(v, h32 + 10);
        p += r6  * __shfl(v, h32 + 12); p += r7  * __shfl(v, h32 + 14);
        p += r8  * __shfl(v, h32 + 16); p += r9  * __shfl(v, h32 + 18);
        p += r10 * __shfl(v, h32 + 20); p += r11 * __shfl(v, h32 + 22);
        p += r12 * __shfl(v, h32 + 24); p += r13 * __shfl(v, h32 + 26);
        p += r14 * __shfl(v, h32 + 28); p += r15 * __shfl(v, h32 + 30);
        float y = p + __shfl_xor(p, 1);          // combine the two column halves
        v += alpha * (mu_r - y);
    }
    if ((lane & 1) == 0) v_out[(size_t)i * KK + (lane >> 1)] = v;
}

// ---------------------------------------------------------------------------
// Kernel 2: per (cluster a, chunk ch): w = mean_g W[i,a,:] (masked);
//   accumulate R += w*v*v^T, s += w*v, Z += w, count += mask over the chunk.
//   Tile of 256 children: thread t reduces child (ib+t)'s 16 g's (one 64B line).
// ---------------------------------------------------------------------------
__global__ __launch_bounds__(256) void k2_accumulate(
    const float* __restrict__ W,
    const float* __restrict__ v,
    float* __restrict__ R_part,
    float* __restrict__ s_part,
    float* __restrict__ Z_part,
    float* __restrict__ cnt_part)
{
    __shared__ float w_lds[TILE];
    __shared__ float v_lds[TILE * KK];
    __shared__ float red_z[4], red_c[4];
    const int a  = blockIdx.x;
    const int ch = blockIdx.y;
    const int t  = threadIdx.x;
    const int k0 = t >> 3;       // row of R this thread owns
    const int l8 = t & 7;        // float4 column group

    float accx = 0.f, accy = 0.f, accz = 0.f, accw = 0.f;
    float s_acc = 0.f, z_acc = 0.f, c_acc = 0.f;

    for (int tile = 0; tile < CHUNK / TILE; ++tile) {   // 2 tiles
        const int ib = ch * CHUNK + tile * TILE;

        // W reduction: one child per thread, 16 g's = 4 float4 = one 64B line
        {
            const float4* wp = (const float4*)(W + (size_t)(ib + t) * (M * G) + a * G);
            float4 w0 = wp[0], w1 = wp[1], w2 = wp[2], w3 = wp[3];
            float sum = w0.x + w0.y + w0.z + w0.w + w1.x + w1.y + w1.z + w1.w
                      + w2.x + w2.y + w2.z + w2.w + w3.x + w3.y + w3.z + w3.w;
            float wsc = sum * (1.0f / G);
            bool  mk  = wsc >= W_EPS;
            float wm  = mk ? wsc : 0.0f;
            w_lds[t] = wm;
            z_acc += wm;
            c_acc += mk ? 1.0f : 0.0f;
        }
        // stage v tile (coalesced float4)
        #pragma unroll
        for (int p = 0; p < TILE * KK / 4 / 256; ++p)   // 8
            ((float4*)v_lds)[p * 256 + t] = ((const float4*)v)[(size_t)ib * 8 + p * 256 + t];
        __syncthreads();

        for (int ii = 0; ii < TILE; ++ii) {
            float w  = w_lds[ii];                          // broadcast
            float vk = v_lds[ii * KK + k0];                // 8-lane broadcast/bank
            float4 vl = ((const float4*)v_lds)[ii * 8 + l8];
            float wv = w * vk;
            accx += wv * vl.x; accy += wv * vl.y;
            accz += wv * vl.z; accw += wv * vl.w;
            if (l8 == 0) s_acc += wv;
        }
        __syncthreads();
    }

    float4 o; o.x = accx; o.y = accy; o.z = accz; o.w = accw;
    ((float4*)R_part)[((size_t)a * NCH + ch) * 256 + t] = o;
    if (l8 == 0) s_part[((size_t)a * NCH + ch) * KK + k0] = s_acc;

    #pragma unroll
    for (int off = 32; off >= 1; off >>= 1) {
        z_acc += __shfl_down(z_acc, off);
        c_acc += __shfl_down(c_acc, off);
    }
    if ((t & 63) == 0) { red_z[t >> 6] = z_acc; red_c[t >> 6] = c_acc; }
    __syncthreads();
    if (t == 0) {
        Z_part[(size_t)a * NCH + ch]   = red_z[0] + red_z[1] + red_z[2] + red_z[3];
        cnt_part[(size_t)a * NCH + ch] = red_c[0] + red_c[1] + red_c[2] + red_c[3];
    }
}

// ---------------------------------------------------------------------------
// Kernel 3: per cluster a: op = mean_g omega_parent; reduce partials;
//   t = op@s; qr = <op^T op, R>; psi = qr/Zs - 2|t|^2/Zs^2 + Z|t|^2/Zs^3,
//   gated on count >= 2. Final scalars in double.
// ---------------------------------------------------------------------------
__global__ __launch_bounds__(256) void k3_finalize(
    const float* __restrict__ omega_parent,
    const float* __restrict__ R_part,
    const float* __restrict__ s_part,
    const float* __restrict__ Z_part,
    const float* __restrict__ cnt_part,
    float* __restrict__ out)
{
    __shared__ float op_lds[KK * KK];
    __shared__ float R_lds[KK * KK];
    __shared__ float s_lds[KK];
    __shared__ float t_lds[KK];
    __shared__ float zc[2];
    __shared__ double dred[4];
    const int a = blockIdx.x;
    const int t = threadIdx.x;

    {   // reduce omega_parent over G
        const float4* src4 = (const float4*)omega_parent + (size_t)a * (G * KK * KK / 4);
        float ax = 0.f, ay = 0.f, az = 0.f, aw = 0.f;
        #pragma unroll
        for (int g = 0; g < G; ++g) {
            float4 x = src4[g * (KK * KK / 4) + t];
            ax += x.x; ay += x.y; az += x.z; aw += x.w;
        }
        const float s = 1.0f / G;
        float4 o; o.x = ax * s; o.y = ay * s; o.z = az * s; o.w = aw * s;
        ((float4*)op_lds)[t] = o;
    }
    {   // reduce R partials
        float ax = 0.f, ay = 0.f, az = 0.f, aw = 0.f;
        #pragma unroll
        for (int c = 0; c < NCH; ++c) {
            float4 x = ((const float4*)R_part)[((size_t)a * NCH + c) * 256 + t];
            ax += x.x; ay += x.y; az += x.z; aw += x.w;
        }
        float4 o; o.x = ax; o.y = ay; o.z = az; o.w = aw;
        ((float4*)R_lds)[t] = o;
    }
    if (t < KK) {
        float sv = 0.f;
        #pragma unroll
        for (int c = 0; c < NCH; ++c) sv += s_part[((size_t)a * NCH + c) * KK + t];
        s_lds[t] = sv;
    }
    if (t == 0) {
        float Z = 0.f, C = 0.f;
        #pragma unroll
        for (int c = 0; c < NCH; ++c) { Z += Z_part[a * NCH + c]; C += cnt_part[a * NCH + c]; }
        zc[0] = Z; zc[1] = C;
    }
    __syncthreads();

    if (t < KK) {   // t_vec = op @ s
        float tv = 0.f;
        #pragma unroll
        for (int l = 0; l < KK; ++l) tv += op_lds[t * KK + l] * s_lds[l];
        t_lds[t] = tv;
    }

    // <Q,R> with Q = op^T op: thread owns (j, 4 l's) of (op@R) dotted with op
    const int j  = t >> 3;
    const int l8 = t & 7;
    float dx = 0.f, dy = 0.f, dz = 0.f, dw = 0.f;
    #pragma unroll
    for (int k = 0; k < KK; ++k) {
        float o = op_lds[j * KK + k];
        float4 rr = ((const float4*)R_lds)[k * 8 + l8];
        dx += o * rr.x; dy += o * rr.y; dz += o * rr.z; dw += o * rr.w;
    }
    const int l0 = l8 * 4;
    double part = (double)dx * op_lds[j * KK + l0]
                + (double)dy * op_lds[j * KK + l0 + 1]
                + (double)dz * op_lds[j * KK + l0 + 2]
                + (double)dw * op_lds[j * KK + l0 + 3];
    #pragma unroll
    for (int off = 32; off >= 1; off >>= 1) part += __shfl_down(part, off);
    if ((t & 63) == 0) dred[t >> 6] = part;
    __syncthreads();

    if (t == 0) {
        double qr = dred[0] + dred[1] + dred[2] + dred[3];
        double tt = 0.0;
        #pragma unroll
        for (int k = 0; k < KK; ++k) tt += (double)t_lds[k] * (double)t_lds[k];
        double Z  = (double)zc[0];
        double C  = (double)zc[1];
        double Zs = (Z > 0.0) ? Z : 1.0;
        double psi = qr / Zs - 2.0 * tt / (Zs * Zs) + Z * tt / (Zs * Zs * Zs);
        out[a] = (C >= 2.0) ? (float)psi : 0.0f;
    }
}

// ---------------------------------------------------------------------------
extern "C" void kernel_launch(void* const* d_in, const int* in_sizes, int n_in,
                              void* d_out, int out_size, void* d_ws, size_t ws_size,
                              hipStream_t stream) {
    const float* W_in  = (const float*)d_in[0];   // (N, M, G)
    const float* mu_in = (const float*)d_in[1];   // (N, G, K)
    const float* oc_in = (const float*)d_in[2];   // (N, G, K, K)
    const float* op_in = (const float*)d_in[3];   // (M, G, K, K)
    float* out = (float*)d_out;                   // (M,)

    float* v        = (float*)d_ws;                       // N*K
    float* R_part   = v + (size_t)N * KK;                 // M*NCH*K*K
    float* s_part   = R_part + (size_t)M * NCH * KK * KK; // M*NCH*K
    float* Z_part   = s_part + (size_t)M * NCH * KK;      // M*NCH
    float* cnt_part = Z_part + (size_t)M * NCH;           // M*NCH

    k1_reduce_solve<<<N / 4, 256, 0, stream>>>(oc_in, mu_in, v);
    k2_accumulate<<<dim3(M, NCH), 256, 0, stream>>>(W_in, v, R_part, s_part, Z_part, cnt_part);
    k3_finalize<<<M, 256, 0, stream>>>(op_in, R_part, s_part, Z_part, cnt_part, out);
}

// Round 4
// 449.576 us; speedup vs baseline: 4.5287x; 1.0675x over previous
//
#include <hip/hip_runtime.h>
#include <hip/hip_bf16.h>

#define N 4096
#define M 128
#define KK 32
#define G 16
#define NCH 8
#define CHUNK (N / NCH)   // 512
#define TILE 256
#define WI 16             // i-tile of the W transpose kernel
#define W_EPS 1e-6f
#define NIT 20
#define ALPHA 0.482f      // 2/(a+b) for spectrum [1.45, 2.70]; rho ~ 0.30

// ---------------------------------------------------------------------------
// Kernel A: streaming G-reduction. Block i, thread t sums omega_child[i,g,:,:]
// at float4 slot t over g (each instruction: 256 threads x 16B contiguous).
// b[16] buffer forces 16 in-flight loads (MLP), ~80 VGPR.
// ---------------------------------------------------------------------------
__global__ __launch_bounds__(256) void kA_reduce(
    const float* __restrict__ oc_in, const float* __restrict__ mu_in,
    float* __restrict__ oc_avg, float* __restrict__ mu_avg)
{
    const int i = blockIdx.x;
    const int t = threadIdx.x;
    const float inv_g = 1.0f / G;

    const float4* src = (const float4*)oc_in + (size_t)i * (G * KK * KK / 4) + t;
    float4 b[G];
    #pragma unroll
    for (int g = 0; g < G; ++g) b[g] = src[g * (KK * KK / 4)];

    float ax = 0.f, ay = 0.f, az = 0.f, aw = 0.f;
    #pragma unroll
    for (int g = 0; g < G; ++g) { ax += b[g].x; ay += b[g].y; az += b[g].z; aw += b[g].w; }
    float4 o; o.x = ax * inv_g; o.y = ay * inv_g; o.z = az * inv_g; o.w = aw * inv_g;
    ((float4*)oc_avg)[(size_t)i * (KK * KK / 4) + t] = o;

    if (t < KK) {   // mu reduction: 128B coalesced per g
        const float* mp = mu_in + (size_t)i * (G * KK) + t;
        float m = 0.f;
        #pragma unroll
        for (int g = 0; g < G; ++g) m += mp[g * KK];
        mu_avg[(size_t)i * KK + t] = m * inv_g;
    }
}

// ---------------------------------------------------------------------------
// Kernel W: transpose-reduce W (N,M,G) -> Wt (M,N). Block = 16 i's x 128 a's.
// Reads 64B/thread contiguous across a (coalesced 8KB rows); LDS transpose
// (stride-17 pad); writes 64B chunks of Wt rows.
// ---------------------------------------------------------------------------
__global__ __launch_bounds__(256) void kW_transpose(
    const float* __restrict__ Wf, float* __restrict__ Wt)
{
    __shared__ float lds[M * 17];
    const int i0 = blockIdx.x * WI;
    const int t  = threadIdx.x;
    const int a  = t & 127;
    const int ih = t >> 7;

    for (int il = ih; il < WI; il += 2) {
        const float4* wp = (const float4*)(Wf + ((size_t)(i0 + il) * M + a) * G);
        float4 w0 = wp[0], w1 = wp[1], w2 = wp[2], w3 = wp[3];
        float s = w0.x + w0.y + w0.z + w0.w + w1.x + w1.y + w1.z + w1.w
                + w2.x + w2.y + w2.z + w2.w + w3.x + w3.y + w3.z + w3.w;
        lds[a * 17 + il] = s * (1.0f / G);
    }
    __syncthreads();

    const int il = t & 15;
    const int a0 = t >> 4;
    for (int aa = a0; aa < M; aa += 16)
        Wt[(size_t)aa * N + i0 + il] = lds[aa * 17 + il];
}

// ---------------------------------------------------------------------------
// Kernel S: one wave per child. Lane l holds floats [16l,16l+16) of oc_avg
// (row l>>1, col-half l&1). Richardson: v <- v + alpha*(mu - oc*v).
// ---------------------------------------------------------------------------
__global__ __launch_bounds__(256) void kS_solve(
    const float* __restrict__ oc_avg, const float* __restrict__ mu_avg,
    float* __restrict__ v_out)
{
    const int wave = threadIdx.x >> 6;
    const int lane = threadIdx.x & 63;
    const int i = blockIdx.x * 4 + wave;

    const float4* src = (const float4*)(oc_avg + (size_t)i * KK * KK) + lane * 4;
    float4 x0 = src[0], x1 = src[1], x2 = src[2], x3 = src[3];
    const float r0 = x0.x, r1 = x0.y, r2  = x0.z, r3  = x0.w;
    const float r4 = x1.x, r5 = x1.y, r6  = x1.z, r7  = x1.w;
    const float r8 = x2.x, r9 = x2.y, r10 = x2.z, r11 = x2.w;
    const float r12 = x3.x, r13 = x3.y, r14 = x3.z, r15 = x3.w;

    const float muc  = mu_avg[(size_t)i * KK + (lane & 31)];
    const float mu_r = __shfl(muc, lane >> 1);   // mu for my row r = lane>>1

    const int h32 = (lane & 1) << 5;             // column-half offset in source lanes
    float v = ALPHA * mu_r;
    #pragma unroll 1
    for (int it = 0; it < NIT; ++it) {
        float p = 0.f;
        // v_c (c = 16h + j) lives in lane 2c = 32h + 2j
        p += r0  * __shfl(v, h32 +  0); p += r1  * __shfl(v, h32 +  2);
        p += r2  * __shfl(v, h32 +  4); p += r3  * __shfl(v, h32 +  6);
        p += r4  * __shfl(v, h32 +  8); p += r5  * __shfl(v, h32 + 10);
        p += r6  * __shfl(v, h32 + 12); p += r7  * __shfl(v, h32 + 14);
        p += r8  * __shfl(v, h32 + 16); p += r9  * __shfl(v, h32 + 18);
        p += r10 * __shfl(v, h32 + 20); p += r11 * __shfl(v, h32 + 22);
        p += r12 * __shfl(v, h32 + 24); p += r13 * __shfl(v, h32 + 26);
        p += r14 * __shfl(v, h32 + 28); p += r15 * __shfl(v, h32 + 30);
        float y = p + __shfl_xor(p, 1);          // combine the two column halves
        v += ALPHA * (mu_r - y);
    }
    if ((lane & 1) == 0) v_out[(size_t)i * KK + (lane >> 1)] = v;
}

// ---------------------------------------------------------------------------
// Kernel 2: per (cluster a, chunk ch): coalesced w from Wt, masked;
//   accumulate R += w*v*v^T, s += w*v, Z += w, count += mask.
// ---------------------------------------------------------------------------
__global__ __launch_bounds__(256) void k2_accumulate(
    const float* __restrict__ Wt,
    const float* __restrict__ v,
    float* __restrict__ R_part,
    float* __restrict__ s_part,
    float* __restrict__ Z_part,
    float* __restrict__ cnt_part)
{
    __shared__ float w_lds[TILE];
    __shared__ float v_lds[TILE * KK];
    __shared__ float red_z[4], red_c[4];
    const int a  = blockIdx.x;
    const int ch = blockIdx.y;
    const int t  = threadIdx.x;
    const int k0 = t >> 3;       // row of R this thread owns
    const int l8 = t & 7;        // float4 column group

    float accx = 0.f, accy = 0.f, accz = 0.f, accw = 0.f;
    float s_acc = 0.f, z_acc = 0.f, c_acc = 0.f;

    for (int tile = 0; tile < CHUNK / TILE; ++tile) {   // 2 tiles
        const int ib = ch * CHUNK + tile * TILE;

        {   // coalesced w load from the transposed reduction
            float wsc = Wt[(size_t)a * N + ib + t];
            bool  mk  = wsc >= W_EPS;
            float wm  = mk ? wsc : 0.0f;
            w_lds[t] = wm;
            z_acc += wm;
            c_acc += mk ? 1.0f : 0.0f;
        }
        #pragma unroll
        for (int p = 0; p < TILE * KK / 4 / 256; ++p)   // 8
            ((float4*)v_lds)[p * 256 + t] = ((const float4*)v)[(size_t)ib * 8 + p * 256 + t];
        __syncthreads();

        for (int ii = 0; ii < TILE; ++ii) {
            float w  = w_lds[ii];
            float vk = v_lds[ii * KK + k0];
            float4 vl = ((const float4*)v_lds)[ii * 8 + l8];
            float wv = w * vk;
            accx += wv * vl.x; accy += wv * vl.y;
            accz += wv * vl.z; accw += wv * vl.w;
            if (l8 == 0) s_acc += wv;
        }
        __syncthreads();
    }

    float4 o; o.x = accx; o.y = accy; o.z = accz; o.w = accw;
    ((float4*)R_part)[((size_t)a * NCH + ch) * 256 + t] = o;
    if (l8 == 0) s_part[((size_t)a * NCH + ch) * KK + k0] = s_acc;

    #pragma unroll
    for (int off = 32; off >= 1; off >>= 1) {
        z_acc += __shfl_down(z_acc, off);
        c_acc += __shfl_down(c_acc, off);
    }
    if ((t & 63) == 0) { red_z[t >> 6] = z_acc; red_c[t >> 6] = c_acc; }
    __syncthreads();
    if (t == 0) {
        Z_part[(size_t)a * NCH + ch]   = red_z[0] + red_z[1] + red_z[2] + red_z[3];
        cnt_part[(size_t)a * NCH + ch] = red_c[0] + red_c[1] + red_c[2] + red_c[3];
    }
}

// ---------------------------------------------------------------------------
// Kernel 3: per cluster a: op = mean_g omega_parent; reduce partials;
//   t = op@s; qr = <op^T op, R>; psi = qr/Zs - 2|t|^2/Zs^2 + Z|t|^2/Zs^3,
//   gated on count >= 2. Final scalars in double.
// ---------------------------------------------------------------------------
__global__ __launch_bounds__(256) void k3_finalize(
    const float* __restrict__ omega_parent,
    const float* __restrict__ R_part,
    const float* __restrict__ s_part,
    const float* __restrict__ Z_part,
    const float* __restrict__ cnt_part,
    float* __restrict__ out)
{
    __shared__ float op_lds[KK * KK];
    __shared__ float R_lds[KK * KK];
    __shared__ float s_lds[KK];
    __shared__ float t_lds[KK];
    __shared__ float zc[2];
    __shared__ double dred[4];
    const int a = blockIdx.x;
    const int t = threadIdx.x;

    {   // reduce omega_parent over G
        const float4* src4 = (const float4*)omega_parent + (size_t)a * (G * KK * KK / 4);
        float ax = 0.f, ay = 0.f, az = 0.f, aw = 0.f;
        #pragma unroll
        for (int g = 0; g < G; ++g) {
            float4 x = src4[g * (KK * KK / 4) + t];
            ax += x.x; ay += x.y; az += x.z; aw += x.w;
        }
        const float s = 1.0f / G;
        float4 o; o.x = ax * s; o.y = ay * s; o.z = az * s; o.w = aw * s;
        ((float4*)op_lds)[t] = o;
    }
    {   // reduce R partials
        float ax = 0.f, ay = 0.f, az = 0.f, aw = 0.f;
        #pragma unroll
        for (int c = 0; c < NCH; ++c) {
            float4 x = ((const float4*)R_part)[((size_t)a * NCH + c) * 256 + t];
            ax += x.x; ay += x.y; az += x.z; aw += x.w;
        }
        float4 o; o.x = ax; o.y = ay; o.z = az; o.w = aw;
        ((float4*)R_lds)[t] = o;
    }
    if (t < KK) {
        float sv = 0.f;
        #pragma unroll
        for (int c = 0; c < NCH; ++c) sv += s_part[((size_t)a * NCH + c) * KK + t];
        s_lds[t] = sv;
    }
    if (t == 0) {
        float Z = 0.f, C = 0.f;
        #pragma unroll
        for (int c = 0; c < NCH; ++c) { Z += Z_part[a * NCH + c]; C += cnt_part[a * NCH + c]; }
        zc[0] = Z; zc[1] = C;
    }
    __syncthreads();

    if (t < KK) {   // t_vec = op @ s
        float tv = 0.f;
        #pragma unroll
        for (int l = 0; l < KK; ++l) tv += op_lds[t * KK + l] * s_lds[l];
        t_lds[t] = tv;
    }

    // <Q,R> with Q = op^T op: thread owns (j, 4 l's) of (op@R) dotted with op
    const int j  = t >> 3;
    const int l8 = t & 7;
    float dx = 0.f, dy = 0.f, dz = 0.f, dw = 0.f;
    #pragma unroll
    for (int k = 0; k < KK; ++k) {
        float o = op_lds[j * KK + k];
        float4 rr = ((const float4*)R_lds)[k * 8 + l8];
        dx += o * rr.x; dy += o * rr.y; dz += o * rr.z; dw += o * rr.w;
    }
    const int l0 = l8 * 4;
    double part = (double)dx * op_lds[j * KK + l0]
                + (double)dy * op_lds[j * KK + l0 + 1]
                + (double)dz * op_lds[j * KK + l0 + 2]
                + (double)dw * op_lds[j * KK + l0 + 3];
    #pragma unroll
    for (int off = 32; off >= 1; off >>= 1) part += __shfl_down(part, off);
    if ((t & 63) == 0) dred[t >> 6] = part;
    __syncthreads();

    if (t == 0) {
        double qr = dred[0] + dred[1] + dred[2] + dred[3];
        double tt = 0.0;
        #pragma unroll
        for (int k = 0; k < KK; ++k) tt += (double)t_lds[k] * (double)t_lds[k];
        double Z  = (double)zc[0];
        double C  = (double)zc[1];
        double Zs = (Z > 0.0) ? Z : 1.0;
        double psi = qr / Zs - 2.0 * tt / (Zs * Zs) + Z * tt / (Zs * Zs * Zs);
        out[a] = (C >= 2.0) ? (float)psi : 0.0f;
    }
}

// ---------------------------------------------------------------------------
extern "C" void kernel_launch(void* const* d_in, const int* in_sizes, int n_in,
                              void* d_out, int out_size, void* d_ws, size_t ws_size,
                              hipStream_t stream) {
    const float* W_in  = (const float*)d_in[0];   // (N, M, G)
    const float* mu_in = (const float*)d_in[1];   // (N, G, K)
    const float* oc_in = (const float*)d_in[2];   // (N, G, K, K)
    const float* op_in = (const float*)d_in[3];   // (M, G, K, K)
    float* out = (float*)d_out;                   // (M,)

    // workspace layout (floats), total ~23 MB; every element written before read
    float* oc_avg   = (float*)d_ws;                        // N*K*K   (16 MB)
    float* mu_avg   = oc_avg + (size_t)N * KK * KK;        // N*K
    float* Wt       = mu_avg + (size_t)N * KK;             // M*N     (2 MB)
    float* v        = Wt + (size_t)M * N;                  // N*K
    float* R_part   = v + (size_t)N * KK;                  // M*NCH*K*K (4 MB)
    float* s_part   = R_part + (size_t)M * NCH * KK * KK;  // M*NCH*K
    float* Z_part   = s_part + (size_t)M * NCH * KK;       // M*NCH
    float* cnt_part = Z_part + (size_t)M * NCH;            // M*NCH

    kA_reduce   <<<N, 256, 0, stream>>>(oc_in, mu_in, oc_avg, mu_avg);
    kW_transpose<<<N / WI, 256, 0, stream>>>(W_in, Wt);
    kS_solve    <<<N / 4, 256, 0, stream>>>(oc_avg, mu_avg, v);
    k2_accumulate<<<dim3(M, NCH), 256, 0, stream>>>(Wt, v, R_part, s_part, Z_part, cnt_part);
    k3_finalize <<<M, 256, 0, stream>>>(op_in, R_part, s_part, Z_part, cnt_part, out);
}